// Round 1
// baseline (152.476 us; speedup 1.0000x reference)
//
#include <hip/hip_runtime.h>
#include <math.h>

#define NSTEP 10

__device__ __forceinline__ void euler2mat(float x, float y, float z, float R[9]) {
    float sx, cx, sy, cy, sz, cz;
    __sincosf(x, &sx, &cx);
    __sincosf(y, &sy, &cy);
    __sincosf(z, &sz, &cz);
    R[0] = cz * cy; R[1] = cz * sy * sx - sz * cx; R[2] = cz * sy * cx + sz * sx;
    R[3] = sz * cy; R[4] = sz * sy * sx + cz * cx; R[5] = sz * sy * cx - cz * sx;
    R[6] = -sy;     R[7] = cy * sx;                R[8] = cy * cx;
}

__device__ __forceinline__ void mat2euler(const float M[9], float& ex, float& ey, float& ez) {
    // M[row*3+col]
    float sy = sqrtf(M[0] * M[0] + M[3] * M[3]);
    bool sing = sy < 1e-6f;
    float a0 = sing ? -M[5] : M[7];
    float a1 = sing ?  M[4] : M[8];
    ex = atan2f(a0, a1);
    ey = atan2f(-M[6], sy);
    ez = sing ? 0.0f : atan2f(M[3], M[0]);
}

__global__ __launch_bounds__(256) void cycle_loss_main(
    const float* __restrict__ pred, const float* __restrict__ gt,
    double* __restrict__ acc_out, int batch)
{
    int idx = blockIdx.x * blockDim.x + threadIdx.x;
    float acc = 0.0f;
    if (idx < batch) {
        float p[60], g[60];
        const float4* p4 = reinterpret_cast<const float4*>(pred) + (size_t)idx * 15;
        const float4* g4 = reinterpret_cast<const float4*>(gt)   + (size_t)idx * 15;
        #pragma unroll
        for (int i = 0; i < 15; ++i) {
            float4 a = p4[i];
            p[4*i+0] = a.x; p[4*i+1] = a.y; p[4*i+2] = a.z; p[4*i+3] = a.w;
            float4 b = g4[i];
            g[4*i+0] = b.x; g[4*i+1] = b.y; g[4*i+2] = b.z; g[4*i+3] = b.w;
        }

        // ---- translation part: v0 = t0; v1 = 2 v0; vi = 2 v(i-1) + sum_{k=1}^{i-1} t_k ----
        {
            float vp[3], vg[3], cp[3] = {0,0,0}, cg[3] = {0,0,0};
            #pragma unroll
            for (int c = 0; c < 3; ++c) {
                vp[c] = p[c]; vg[c] = g[c];
                float d = vp[c] - vg[c];
                acc += d * d;
            }
            #pragma unroll
            for (int i = 1; i < NSTEP; ++i) {
                #pragma unroll
                for (int c = 0; c < 3; ++c) {
                    if (i >= 2) { cp[c] += p[6*(i-1)+c]; cg[c] += g[6*(i-1)+c]; }
                    vp[c] = 2.0f * vp[c] + cp[c];
                    vg[c] = 2.0f * vg[c] + cg[c];
                    float d = vp[c] - vg[c];
                    acc += d * d;
                }
            }
        }

        // ---- rotation part: P = elementwise cumprod of R (exclusive); M_i = R1 ⊙ P_i ----
        {
            float R1p[9], R1g[9];
            euler2mat(p[9],  p[10], p[11], R1p);
            euler2mat(g[9],  g[10], g[11], R1g);
            float Pp[9], Pg[9];
            #pragma unroll
            for (int k = 0; k < 9; ++k) { Pp[k] = 1.0f; Pg[k] = 1.0f; }
            #pragma unroll
            for (int i = 0; i < NSTEP; ++i) {
                float Mp[9], Mg[9];
                #pragma unroll
                for (int k = 0; k < 9; ++k) { Mp[k] = R1p[k] * Pp[k]; Mg[k] = R1g[k] * Pg[k]; }
                float xp, yp, zp, xg, yg, zg;
                mat2euler(Mp, xp, yp, zp);
                mat2euler(Mg, xg, yg, zg);
                float dx = xp - xg, dy = yp - yg, dz = zp - zg;
                acc += dx * dx + dy * dy + dz * dz;
                if (i < NSTEP - 1) {
                    float Rp[9], Rg[9];
                    euler2mat(p[6*i+3], p[6*i+4], p[6*i+5], Rp);
                    euler2mat(g[6*i+3], g[6*i+4], g[6*i+5], Rg);
                    #pragma unroll
                    for (int k = 0; k < 9; ++k) { Pp[k] *= Rp[k]; Pg[k] *= Rg[k]; }
                }
            }
        }
    }

    // ---- reduction: wave shuffle -> LDS -> one double atomic per block ----
    int lane = threadIdx.x & 63;
    int wid  = threadIdx.x >> 6;
    #pragma unroll
    for (int off = 32; off > 0; off >>= 1)
        acc += __shfl_down(acc, off, 64);
    __shared__ float warp_s[4];
    if (lane == 0) warp_s[wid] = acc;
    __syncthreads();
    if (threadIdx.x == 0) {
        float s = warp_s[0] + warp_s[1] + warp_s[2] + warp_s[3];
        atomicAdd(acc_out, (double)s);
    }
}

__global__ void cycle_loss_fin(const double* __restrict__ acc, float* __restrict__ out, double inv) {
    out[0] = (float)(acc[0] * inv);
}

extern "C" void kernel_launch(void* const* d_in, const int* in_sizes, int n_in,
                              void* d_out, int out_size, void* d_ws, size_t ws_size,
                              hipStream_t stream) {
    const float* pred = (const float*)d_in[0];
    const float* gt   = (const float*)d_in[1];
    int batch = in_sizes[0] / 60;
    double* acc = (double*)d_ws;

    hipMemsetAsync(acc, 0, sizeof(double), stream);

    const int threads = 256;
    const int blocks = (batch + threads - 1) / threads;
    cycle_loss_main<<<blocks, threads, 0, stream>>>(pred, gt, acc, batch);

    double inv = 1.0 / (60.0 * (double)batch * (double)batch);
    cycle_loss_fin<<<1, 1, 0, stream>>>(acc, (float*)d_out, inv);
}